// Round 4
// baseline (1699.249 us; speedup 1.0000x reference)
//
#include <hip/hip_runtime.h>

// QLSTM, T=512, B=256, IN=128, HID=256, NQ=32, D=384.
//
// Decomposition:
//  k0: transpose Wg_x (128x128) into wsT[k][gn]  (stored in out-tail scratch)
//  k1: z_x[t,b,gn] = x[t,b,:].Wgx[gn,:]  -- parallel fp32 GEMM, no recurrence.
//      Written into out[t*B*256 + b*256 + gn] (first 128 floats of each (t,b)
//      out-slot; consumed at step t by k2, then overwritten by h outputs).
//  k2: serial recurrence, 1 block/batch row, 512 thr (2 waves/SIMD).
//      Per step: z[gn] = z_x + bias + h.Wgh[gn,:] (K=256, Wgh streamed from
//      LDS conflict-free), then h4 = z.Wh^T (Wh in asm-pinned registers),
//      activations, c/h update. 2 barriers/step, z double-buffered,
//      z_x prefetched one step ahead.
//
// Round 1-3 lesson baked in: NO large per-thread weight arrays; the only
// register array (wh[32]) is made opaque via asm so hipcc cannot re-load it
// from global inside the t-loop (VGPR=64/84 in r2/r3 proved it does that).

#define T_STEPS 512
#define BATCH   256
#define INDIM   128
#define HIDDEN  256
#define GN      128
#define OUT_MAIN ((size_t)T_STEPS * BATCH * HIDDEN)

__device__ __forceinline__ float sigmoid_f(float x) {
    return 1.0f / (1.0f + __expf(-x));
}
__device__ __forceinline__ float tanh_f(float x) {
    float e = __expf(2.0f * x);
    return (e - 1.0f) / (e + 1.0f);
}

// ---------------- k0: Wg_x transpose -> wsT[k][gn] ----------------
__global__ void k0_transpose(const float* __restrict__ Wg, float* __restrict__ wsT) {
    int idx = blockIdx.x * 256 + threadIdx.x;   // 16384
    int gn = idx & 127, k = idx >> 7;
    wsT[idx] = Wg[gn * 384 + k];
}

// ---------------- k1: z_x GEMM (M=T*B=131072, N=128, K=128) ----------------
// block: 256 thr, tile M=128 x N=128, K in 4 chunks of 32.
__global__ __launch_bounds__(256) void k1_zx(const float* __restrict__ x,
                                             const float* __restrict__ wsT,
                                             float* __restrict__ out) {
    __shared__ float xs[128 * 32];   // [row][k]
    __shared__ float ws[32 * 128];   // [k][gn]
    const int tid  = threadIdx.x;
    const int row0 = blockIdx.x * 128;
    const int tx   = tid & 31;       // gn quad: gn = tx*4
    const int ty   = tid >> 5;       // rows ty*16 .. +16

    float4 acc[16];
    #pragma unroll
    for (int r = 0; r < 16; ++r) acc[r] = make_float4(0.f, 0.f, 0.f, 0.f);

    for (int c = 0; c < 4; ++c) {
        __syncthreads();   // protect previous chunk's reads
        #pragma unroll
        for (int i = 0; i < 4; ++i) {           // stage xs (rows x 32 k)
            int fidx = i * 256 + tid;
            int row = fidx >> 3, q = fidx & 7;
            *reinterpret_cast<float4*>(&xs[row * 32 + q * 4]) =
                *reinterpret_cast<const float4*>(
                    &x[(size_t)(row0 + row) * INDIM + c * 32 + q * 4]);
        }
        #pragma unroll
        for (int i = 0; i < 4; ++i) {           // stage ws chunk (linear)
            int fidx = i * 256 + tid;
            *reinterpret_cast<float4*>(&ws[fidx * 4]) =
                *reinterpret_cast<const float4*>(&wsT[(size_t)c * 4096 + fidx * 4]);
        }
        __syncthreads();

        #pragma unroll
        for (int kk = 0; kk < 32; kk += 4) {
            float4 b0 = *reinterpret_cast<const float4*>(&ws[(kk + 0) * 128 + tx * 4]);
            float4 b1 = *reinterpret_cast<const float4*>(&ws[(kk + 1) * 128 + tx * 4]);
            float4 b2 = *reinterpret_cast<const float4*>(&ws[(kk + 2) * 128 + tx * 4]);
            float4 b3 = *reinterpret_cast<const float4*>(&ws[(kk + 3) * 128 + tx * 4]);
            #pragma unroll
            for (int r = 0; r < 16; ++r) {
                float4 a = *reinterpret_cast<const float4*>(&xs[(ty * 16 + r) * 32 + kk]);
                acc[r].x += a.x * b0.x + a.y * b1.x + a.z * b2.x + a.w * b3.x;
                acc[r].y += a.x * b0.y + a.y * b1.y + a.z * b2.y + a.w * b3.y;
                acc[r].z += a.x * b0.z + a.y * b1.z + a.z * b2.z + a.w * b3.z;
                acc[r].w += a.x * b0.w + a.y * b1.w + a.z * b2.w + a.w * b3.w;
            }
        }
    }
    #pragma unroll
    for (int r = 0; r < 16; ++r)
        *reinterpret_cast<float4*>(&out[(size_t)(row0 + ty * 16 + r) * 256 + tx * 4]) = acc[r];
}

// ---------------- k2: recurrence ----------------
// dynamic LDS (floats): wgh[64][128][4] (=32768) | comb_h[256] | zbuf[2][144]
#define WGH_OFF   0
#define COMB_OFF  32768
#define ZBUF_OFF  (32768 + 256)
#define LDS_FLOATS (ZBUF_OFF + 2 * 144)
#define LDS_BYTES  (LDS_FLOATS * 4)
#define ZPAD(i) ((i) + (((i) >> 5) << 2))

__global__ __launch_bounds__(512, 2) void qlstm_kernel(
    const float* __restrict__ Wg,   // (4,32,384)
    const float* __restrict__ bg,   // (4,32)
    const float* __restrict__ Wh,   // (256,32)
    const float* __restrict__ bh,   // (256)
    float* __restrict__ out)        // zx pre-written in main region by k1
{
    extern __shared__ float lds[];
    float* wgh  = lds + WGH_OFF;
    float* comb = lds + COMB_OFF;   // h only (256)
    float* zbuf = lds + ZBUF_OFF;

    const int tid = threadIdx.x;
    const int b   = blockIdx.x;
    const int gn  = tid & 127;
    const int kq  = tid >> 7;       // wave-uniform K-quarter
    const int h2  = tid >> 1;
    const int gh  = tid & 1;

    // one-time: Wg_h -> LDS, layout [k4][gn][4]; coalesced global reads
    #pragma unroll
    for (int i = 0; i < 64; ++i) {
        int e = i * 512 + tid;
        int g = e >> 8;          // gn
        int k = e & 255;
        wgh[(k >> 2) * 512 + g * 4 + (k & 3)] = Wg[g * 384 + 128 + k];
    }

    // Wh row in registers, pinned opaque so it can't be re-loaded per step
    float wh[32];
    {
        const float4* p = reinterpret_cast<const float4*>(Wh + h2 * 32);
        #pragma unroll
        for (int j4 = 0; j4 < 8; ++j4) {
            float4 v = p[j4];
            wh[4*j4+0] = v.x; wh[4*j4+1] = v.y; wh[4*j4+2] = v.z; wh[4*j4+3] = v.w;
        }
    }
    #pragma unroll
    for (int j4 = 0; j4 < 8; ++j4)
        asm volatile("" : "+v"(wh[4*j4+0]), "+v"(wh[4*j4+1]),
                          "+v"(wh[4*j4+2]), "+v"(wh[4*j4+3]));

    const float bg0 = (tid < 128) ? bg[tid] : 0.0f;
    const float bhv = bh[h2];

    float c = 0.0f, hval = 0.0f;
    if (tid < HIDDEN) comb[tid] = 0.0f;   // h0 = 0

    // z_x lives at out[t*B*256 + b*256 + gn] (gn < 128)
    const float* zx  = out + (size_t)b * 256 + tid;          // valid for tid<128
    float*       outb = out + (size_t)b * HIDDEN;

    float zxreg = (tid < 128) ? zx[0] : 0.0f;   // t = 0

    for (int t = 0; t < T_STEPS; ++t) {
        float* zq = zbuf + (t & 1) * 144;

        if (tid < 128) zq[ZPAD(tid)] = zxreg + bg0;
        __syncthreads();
        // (orders: wgh fill & h0 at t=0; prev h writes; z init; prev-z reads)

        if (tid < 128 && t + 1 < T_STEPS)
            zxreg = zx[(size_t)(t + 1) * (BATCH * 256)];     // prefetch, hidden

        // stage 1: z[gn] += h . Wgh[gn, kq*64 .. +64)
        float a0 = 0.f, a1 = 0.f, a2 = 0.f, a3 = 0.f;
        const float4* wrow = reinterpret_cast<const float4*>(wgh) + kq * 16 * 128 + gn;
        const float4* hrow = reinterpret_cast<const float4*>(comb) + kq * 16;
        #pragma unroll
        for (int j4 = 0; j4 < 16; ++j4) {
            float4 w  = wrow[(size_t)j4 * 128];   // conflict-free b128
            float4 hv = hrow[j4];                 // wave-uniform broadcast
            a0 += w.x * hv.x; a1 += w.y * hv.y;
            a2 += w.z * hv.z; a3 += w.w * hv.w;
        }
        atomicAdd(&zq[ZPAD(gn)], (a0 + a1) + (a2 + a3));
        __syncthreads();

        // stage 2: gates {gh, gh+2} for hidden unit h2
        const float* za = zq + 36 * gh;
        const float* zc = zq + 36 * (gh + 2);
        float pa0 = 0.f, pa1 = 0.f, pb0 = 0.f, pb1 = 0.f;
        #pragma unroll
        for (int n = 0; n < 32; n += 4) {
            float4 va = *reinterpret_cast<const float4*>(za + n);
            float4 vb = *reinterpret_cast<const float4*>(zc + n);
            pa0 += va.x * wh[n]   + va.y * wh[n+1];
            pa1 += va.z * wh[n+2] + va.w * wh[n+3];
            pb0 += vb.x * wh[n]   + vb.y * wh[n+1];
            pb1 += vb.z * wh[n+2] + vb.w * wh[n+3];
        }
        float pA = pa0 + pa1;   // even: f-pre, odd: i-pre
        float pB = pb0 + pb1;   // even: g-pre, odd: o-pre
        float oA = __shfl_xor(pA, 1);
        float oB = __shfl_xor(pB, 1);
        float pf = gh ? oA : pA;
        float pi = gh ? pA : oA;
        float pg = gh ? oB : pB;
        float po = gh ? pB : oB;

        float fg = sigmoid_f(pf + bhv);
        float ig = sigmoid_f(pi + bhv);
        float gg = tanh_f(pg + bhv);
        float og = sigmoid_f(po + bhv);
        c    = fg * c + ig * gg;           // both lanes replicate c
        hval = og * tanh_f(c);

        if (!gh) {
            comb[h2] = hval;
            outb[(size_t)t * (BATCH * HIDDEN) + h2] = hval;  // overwrites zx[t]
        }
    }

    if (!gh) {
        out[OUT_MAIN + (size_t)b * HIDDEN + h2]                          = hval;
        out[OUT_MAIN + (size_t)BATCH * HIDDEN + (size_t)b * HIDDEN + h2] = c;
    }
}

extern "C" void kernel_launch(void* const* d_in, const int* in_sizes, int n_in,
                              void* d_out, int out_size, void* d_ws, size_t ws_size,
                              hipStream_t stream) {
    const float* x  = (const float*)d_in[0];   // (512,256,128)
    const float* Wg = (const float*)d_in[1];   // (4,32,384)
    const float* bg = (const float*)d_in[2];   // (4,32)
    const float* Wh = (const float*)d_in[3];   // (256,32)
    const float* bh = (const float*)d_in[4];   // (256)
    float* out = (float*)d_out;

    // Wgx^T scratch lives in the out-tail (hx/cx region), overwritten at the
    // very end of k2 — no d_ws dependence.
    float* wsT = out + OUT_MAIN;

    hipFuncSetAttribute((const void*)qlstm_kernel,
                        hipFuncAttributeMaxDynamicSharedMemorySize, LDS_BYTES);

    k0_transpose<<<64, 256, 0, stream>>>(Wg, wsT);
    k1_zx<<<1024, 256, 0, stream>>>(x, wsT, out);
    qlstm_kernel<<<BATCH, 512, LDS_BYTES, stream>>>(Wg, bg, Wh, bh, out);
}

// Round 9
// 704.083 us; speedup vs baseline: 2.4134x; 2.4134x over previous
//
#include <hip/hip_runtime.h>
#include <hip/hip_fp16.h>

// QLSTM recurrence, T=512, B=256, IN=128, HID=256, NQ=32, D=384.
// One block per batch row; 512 threads (8 waves = 2 waves/SIMD).
//
// r1-r4 lesson: the kernel was LDS-instruction-bound (each CU re-streamed
// 131 KB of weights through the LDS pipe every step: ~400 b128 ops = ~5600
// cyc/step). Fix: weights live in REGISTERS, fp16-packed, asm-pinned (r4
// proved pinned regs survive the t-loop); dots use v_dot2_f32_f16 (fp32
// accumulate). LDS now carries only comb(x|h) + z in fp16: ~23 LDS
// instrs/thread/step.
//
// Stage 1: thread (gn=tid>>2, kq=tid&3): 96-half K-slice vs comb broadcast;
//          quad reduce via shfl_xor(1,2); lane kq==0 writes z[gn] fp16.
// Stage 2: thread (h2=tid>>1, gh=tid&1): gates {gh, gh+2} vs pinned Wh row;
//          pair exchange shfl_xor(1); both lanes replicate c.
// 2 barriers/step; single z buffer (writes and reads strictly separated by
// the barriers); x converted to fp16 in-loop with 2-step-ahead prefetch.

#define T_STEPS 512
#define BATCH   256
#define INDIM   128
#define HIDDEN  256
#define OUT_MAIN ((size_t)T_STEPS * BATCH * HIDDEN)

typedef _Float16 f16x2 __attribute__((ext_vector_type(2)));

__device__ __forceinline__ float dot2(unsigned a, unsigned b, float c) {
    return __builtin_amdgcn_fdot2(__builtin_bit_cast(f16x2, a),
                                  __builtin_bit_cast(f16x2, b), c, false);
}
__device__ __forceinline__ unsigned pack2(float a, float b) {
    __half2 h = __floats2half2_rn(a, b);
    return __builtin_bit_cast(unsigned, h);
}
__device__ __forceinline__ float sigmoid_f(float x) {
    return 1.0f / (1.0f + __expf(-x));
}
__device__ __forceinline__ float tanh_f(float x) {
    float e = __expf(2.0f * x);
    return (e - 1.0f) / (e + 1.0f);
}

__global__ __launch_bounds__(512, 2) void qlstm_kernel(
    const float* __restrict__ x,    // (T,B,IN)
    const float* __restrict__ Wg,   // (4,32,384) row-major, row = gn
    const float* __restrict__ bg,   // (4,32) flat [gn]
    const float* __restrict__ Wh,   // (256,32)
    const float* __restrict__ bh,   // (256)
    float* __restrict__ out)        // T*B*HID ++ B*HID ++ B*HID
{
    __shared__ __align__(16) unsigned short comb[384];  // fp16: k<128 = x, k>=128 = h
    __shared__ __align__(16) unsigned short zh[128];    // fp16 z

    const int tid = threadIdx.x;
    const int b   = blockIdx.x;
    const int gn  = tid >> 2;    // stage-1 column (0..127)
    const int kq  = tid & 3;     // stage-1 K-quarter (quad-local!)
    const int h2  = tid >> 1;    // stage-2 hidden unit
    const int gh  = tid & 1;     // stage-2 gate parity

    unsigned* comb_u32 = reinterpret_cast<unsigned*>(comb);

    // ---- one-time: fp16-pack weights into registers, then PIN them ----
    unsigned wgp[48];   // Wg[gn][kq*96 .. +96) as 48 half2
    {
        const float* wrow = Wg + gn * 384 + kq * 96;
        #pragma unroll
        for (int j = 0; j < 48; ++j) wgp[j] = pack2(wrow[2*j], wrow[2*j+1]);
    }
    unsigned whp[16];   // Wh[h2][0..32) as 16 half2
    {
        const float* wr = Wh + h2 * 32;
        #pragma unroll
        for (int j = 0; j < 16; ++j) whp[j] = pack2(wr[2*j], wr[2*j+1]);
    }
    #pragma unroll
    for (int i = 0; i < 48; ++i) asm volatile("" : "+v"(wgp[i]));
    #pragma unroll
    for (int i = 0; i < 16; ++i) asm volatile("" : "+v"(whp[i]));

    const float bg0 = bg[gn];
    const float bhv = bh[h2];

    float c = 0.0f, hval = 0.0f;
    if (tid < 128) comb_u32[64 + tid] = 0u;   // h0 = 0 (fp16 zeros)

    const float* xb   = x + (size_t)b * INDIM;
    float*       outb = out + (size_t)b * HIDDEN;

    // x staging: 64 lanes each own 2 consecutive x elems; 2-step-ahead prefetch
    float2 xA = make_float2(0.f, 0.f), xB = xA;
    if (tid < 64) {
        float2 x0 = *reinterpret_cast<const float2*>(xb + 2 * tid);
        comb_u32[tid] = pack2(x0.x, x0.y);                                  // t=0
        xA = *reinterpret_cast<const float2*>(xb + (size_t)1 * BATCH * INDIM + 2 * tid);
        xB = *reinterpret_cast<const float2*>(xb + (size_t)2 * BATCH * INDIM + 2 * tid);
    }
    __syncthreads();

    for (int t = 0; t < T_STEPS; ++t) {
        // ---- stage 1: z[gn] partial over K-quarter kq (fp16 dot2) ----
        const uint4* cs = reinterpret_cast<const uint4*>(comb) + kq * 12;
        float a0 = 0.f, a1 = 0.f, a2 = 0.f, a3 = 0.f;
        #pragma unroll
        for (int j = 0; j < 12; ++j) {
            uint4 cv = cs[j];                    // 4-addr quad broadcast, 2-way banks
            a0 = dot2(wgp[4*j+0], cv.x, a0);
            a1 = dot2(wgp[4*j+1], cv.y, a1);
            a2 = dot2(wgp[4*j+2], cv.z, a2);
            a3 = dot2(wgp[4*j+3], cv.w, a3);
        }
        float s = (a0 + a1) + (a2 + a3);
        s += __shfl_xor(s, 1);                   // quad-local reduce
        s += __shfl_xor(s, 2);
        if ((tid & 3) == 0)
            zh[gn] = __half_as_ushort(__float2half_rn(s + bg0));
        __syncthreads();   // B1: z visible; comb free to modify

        // stage next x row (for t+1) + advance prefetch pipeline
        if (tid < 64) {
            comb_u32[tid] = pack2(xA.x, xA.y);
            xA = xB;
            int tn = (t + 3 < T_STEPS) ? (t + 3) : (T_STEPS - 1);
            xB = *reinterpret_cast<const float2*>(xb + (size_t)tn * BATCH * INDIM + 2 * tid);
        }

        // ---- stage 2: gates {gh, gh+2} for hidden unit h2 ----
        const uint4* zu = reinterpret_cast<const uint4*>(zh);
        float pa0 = 0.f, pa1 = 0.f, pb0 = 0.f, pb1 = 0.f;
        #pragma unroll
        for (int J = 0; J < 4; ++J) {
            uint4 va = zu[gh * 4 + J];           // gate gh
            uint4 vb = zu[(gh + 2) * 4 + J];     // gate gh+2
            pa0 = dot2(whp[4*J+0], va.x, pa0);
            pa1 = dot2(whp[4*J+1], va.y, pa1);
            pa0 = dot2(whp[4*J+2], va.z, pa0);
            pa1 = dot2(whp[4*J+3], va.w, pa1);
            pb0 = dot2(whp[4*J+0], vb.x, pb0);
            pb1 = dot2(whp[4*J+1], vb.y, pb1);
            pb0 = dot2(whp[4*J+2], vb.z, pb0);
            pb1 = dot2(whp[4*J+3], vb.w, pb1);
        }
        float pA = pa0 + pa1;   // even: f-pre, odd: i-pre
        float pB = pb0 + pb1;   // even: g-pre, odd: o-pre
        float oA = __shfl_xor(pA, 1);
        float oB = __shfl_xor(pB, 1);
        float pf = gh ? oA : pA;
        float pi = gh ? pA : oA;
        float pg = gh ? oB : pB;
        float po = gh ? pB : oB;

        float fg = sigmoid_f(pf + bhv);
        float ig = sigmoid_f(pi + bhv);
        float gg = tanh_f(pg + bhv);
        float og = sigmoid_f(po + bhv);
        c    = fg * c + ig * gg;           // both lanes replicate c
        hval = og * tanh_f(c);

        if (!gh) {
            comb[128 + h2] = __half_as_ushort(__float2half_rn(hval));
            outb[(size_t)t * (BATCH * HIDDEN) + h2] = hval;
        }
        __syncthreads();   // B2: h (and next-x) visible for next stage-1
    }

    if (!gh) {
        out[OUT_MAIN + (size_t)b * HIDDEN + h2]                          = hval;
        out[OUT_MAIN + (size_t)BATCH * HIDDEN + (size_t)b * HIDDEN + h2] = c;
    }
}

extern "C" void kernel_launch(void* const* d_in, const int* in_sizes, int n_in,
                              void* d_out, int out_size, void* d_ws, size_t ws_size,
                              hipStream_t stream) {
    const float* x  = (const float*)d_in[0];   // (512,256,128)
    const float* Wg = (const float*)d_in[1];   // (4,32,384)
    const float* bg = (const float*)d_in[2];   // (4,32)
    const float* Wh = (const float*)d_in[3];   // (256,32)
    const float* bh = (const float*)d_in[4];   // (256)
    float* out = (float*)d_out;

    qlstm_kernel<<<BATCH, 512, 0, stream>>>(x, Wg, bg, Wh, bh, out);
}